// Round 3
// baseline (189.636 us; speedup 1.0000x reference)
//
#include <hip/hip_runtime.h>
#include <math.h>

#define B_   128
#define T_   1024
#define D_   256
#define L_   512

__device__ __forceinline__ float sigmoidf_(float x) {
    return 1.f / (1.f + __expf(-x));
}
__device__ __forceinline__ float tanhf_(float x) {
    x = fminf(fmaxf(x, -15.f), 15.f);
    float e = __expf(2.f * x);
    return (e - 1.f) / (e + 1.f);
}
__device__ __forceinline__ float waveReduceSum(float v) {
    #pragma unroll
    for (int o = 32; o > 0; o >>= 1) v += __shfl_xor(v, o, 64);
    return v;
}
__device__ __forceinline__ float waveReduceMax(float v) {
    #pragma unroll
    for (int o = 32; o > 0; o >>= 1) v = fmaxf(v, __shfl_xor(v, o, 64));
    return v;
}

// ---------------------------------------------------------------------------
// K1 fused: prenet + GRU GEMVs + gates + q.   grid=64 (2 batches/block)
// ---------------------------------------------------------------------------
__global__ __launch_bounds__(256) void k1_fused(
    const float* __restrict__ prenet_in, const float* __restrict__ attn_hidden,
    const float* __restrict__ context_vec,
    const float* __restrict__ fc1_W, const float* __restrict__ fc1_b,
    const float* __restrict__ fc2_W, const float* __restrict__ fc2_b,
    const float* __restrict__ gru_Wih, const float* __restrict__ gru_Whh,
    const float* __restrict__ gru_bih, const float* __restrict__ gru_bhh,
    const float* __restrict__ attn_W,
    float* __restrict__ attn_h_out, float* __restrict__ q_out)
{
    const int t = threadIdx.x;
    const int b0 = blockIdx.x * 2;

    __shared__ __align__(16) float pin[2][80];
    __shared__ __align__(16) float p1[2][256];
    __shared__ __align__(16) float xs[2][384];   // [cvec | prenet_out]
    __shared__ __align__(16) float hs[2][256];
    __shared__ __align__(16) float gi[2][768];
    __shared__ __align__(16) float gh[2][768];
    __shared__ __align__(16) float ahn[2][256];

    if (t < 80) {
        pin[0][t] = prenet_in[b0 * 80 + t];
        pin[1][t] = prenet_in[(b0 + 1) * 80 + t];
    }
    xs[0][t] = context_vec[b0 * 256 + t];
    xs[1][t] = context_vec[(b0 + 1) * 256 + t];
    hs[0][t] = attn_hidden[b0 * 256 + t];
    hs[1][t] = attn_hidden[(b0 + 1) * 256 + t];
    __syncthreads();

    // fc1: 256 outputs, K=80
    {
        float a0 = fc1_b[t], a1 = a0;
        const float4* w  = (const float4*)(fc1_W + t * 80);
        const float4* x0 = (const float4*)pin[0];
        const float4* x1 = (const float4*)pin[1];
        #pragma unroll
        for (int k = 0; k < 20; k++) {
            float4 wv = w[k], v0 = x0[k], v1 = x1[k];
            a0 += v0.x * wv.x + v0.y * wv.y + v0.z * wv.z + v0.w * wv.w;
            a1 += v1.x * wv.x + v1.y * wv.y + v1.z * wv.z + v1.w * wv.w;
        }
        p1[0][t] = fmaxf(a0, 0.f);
        p1[1][t] = fmaxf(a1, 0.f);
    }
    __syncthreads();

    // fc2: 128 outputs, K=256 -> xs[.][256+t]
    if (t < 128) {
        float a0 = fc2_b[t], a1 = a0;
        const float4* w  = (const float4*)(fc2_W + t * 256);
        const float4* x0 = (const float4*)p1[0];
        const float4* x1 = (const float4*)p1[1];
        #pragma unroll 8
        for (int k = 0; k < 64; k++) {
            float4 wv = w[k], v0 = x0[k], v1 = x1[k];
            a0 += v0.x * wv.x + v0.y * wv.y + v0.z * wv.z + v0.w * wv.w;
            a1 += v1.x * wv.x + v1.y * wv.y + v1.z * wv.z + v1.w * wv.w;
        }
        xs[0][256 + t] = fmaxf(a0, 0.f);
        xs[1][256 + t] = fmaxf(a1, 0.f);
    }
    __syncthreads();

    // gi (K=384) and gh (K=256), 3 rows per thread each
    #pragma unroll
    for (int jj = 0; jj < 3; jj++) {
        int j = jj * 256 + t;
        float a0 = gru_bih[j], a1 = a0;
        const float4* w  = (const float4*)(gru_Wih + (size_t)j * 384);
        const float4* x0 = (const float4*)xs[0];
        const float4* x1 = (const float4*)xs[1];
        #pragma unroll 8
        for (int k = 0; k < 96; k++) {
            float4 wv = w[k], v0 = x0[k], v1 = x1[k];
            a0 += v0.x * wv.x + v0.y * wv.y + v0.z * wv.z + v0.w * wv.w;
            a1 += v1.x * wv.x + v1.y * wv.y + v1.z * wv.z + v1.w * wv.w;
        }
        gi[0][j] = a0; gi[1][j] = a1;

        float c0 = gru_bhh[j], c1 = c0;
        const float4* w2 = (const float4*)(gru_Whh + (size_t)j * 256);
        const float4* h0 = (const float4*)hs[0];
        const float4* h1 = (const float4*)hs[1];
        #pragma unroll 8
        for (int k = 0; k < 64; k++) {
            float4 wv = w2[k], v0 = h0[k], v1 = h1[k];
            c0 += v0.x * wv.x + v0.y * wv.y + v0.z * wv.z + v0.w * wv.w;
            c1 += v1.x * wv.x + v1.y * wv.y + v1.z * wv.z + v1.w * wv.w;
        }
        gh[0][j] = c0; gh[1][j] = c1;
    }
    __syncthreads();

    // GRU gates
    #pragma unroll
    for (int bb = 0; bb < 2; bb++) {
        float rg = sigmoidf_(gi[bb][t] + gh[bb][t]);
        float zg = sigmoidf_(gi[bb][256 + t] + gh[bb][256 + t]);
        float ng = tanhf_(gi[bb][512 + t] + rg * gh[bb][512 + t]);
        float h  = (1.f - zg) * ng + zg * hs[bb][t];
        ahn[bb][t] = h;
        attn_h_out[(b0 + bb) * 256 + t] = h;
    }
    __syncthreads();

    // q = attn_h @ attn_W.T
    {
        float a0 = 0.f, a1 = 0.f;
        const float4* w  = (const float4*)(attn_W + (size_t)t * 256);
        const float4* x0 = (const float4*)ahn[0];
        const float4* x1 = (const float4*)ahn[1];
        #pragma unroll 8
        for (int k = 0; k < 64; k++) {
            float4 wv = w[k], v0 = x0[k], v1 = x1[k];
            a0 += v0.x * wv.x + v0.y * wv.y + v0.z * wv.z + v0.w * wv.w;
            a1 += v1.x * wv.x + v1.y * wv.y + v1.z * wv.z + v1.w * wv.w;
        }
        q_out[b0 * 256 + t]       = a0;
        q_out[(b0 + 1) * 256 + t] = a1;
    }
}

// ---------------------------------------------------------------------------
// KA: fused attention pass (flash-style).  grid = B*8 chunks of 128 t.
//   stage1: u[t] = sum_d tanh(encp+q)*v      (wave-reduce, as old k2)
//   stage2: local max m_loc, e[t]=exp(u-m_loc), local sum s_loc
//   stage3: ctx_part[d] = sum_t e[t]*enc[t][d]
// ---------------------------------------------------------------------------
__global__ __launch_bounds__(256) void ka_attn(
    const float* __restrict__ enc_proj, const float* __restrict__ enc,
    const float* __restrict__ q, const float* __restrict__ v,
    float* __restrict__ u_out, float* __restrict__ ctx_part,
    float* __restrict__ m_part, float* __restrict__ s_part)
{
    const int b     = blockIdx.x >> 3;
    const int chunk = blockIdx.x & 7;
    const int tid   = threadIdx.x;
    const int lane  = tid & 63;
    const int wv    = tid >> 6;   // 0..3

    __shared__ float ul[128];
    __shared__ float el[128];
    __shared__ __align__(16) float4 red[4][64];
    __shared__ float mred[2], sred[2];

    float4 qv = ((const float4*)(q + b * 256))[lane];
    float4 vv = ((const float4*)v)[lane];
    const float4* base = (const float4*)enc_proj + ((size_t)(b * T_ + chunk * 128)) * 64;

    // stage 1: u for 128 t's (wave wv owns t in [wv*32, wv*32+32))
    #pragma unroll 4
    for (int i = 0; i < 32; i++) {
        int t = wv * 32 + i;
        float4 pj = base[(size_t)t * 64 + lane];
        float s = tanhf_(pj.x + qv.x) * vv.x + tanhf_(pj.y + qv.y) * vv.y
                + tanhf_(pj.z + qv.z) * vv.z + tanhf_(pj.w + qv.w) * vv.w;
        s = waveReduceSum(s);
        if (lane == 0) ul[t] = s;
    }
    __syncthreads();

    // stage 2a: local max (threads 0..127 = waves 0,1)
    if (tid < 128) {
        float x = ul[tid];
        u_out[b * T_ + chunk * 128 + tid] = x;
        x = waveReduceMax(x);
        if (lane == 0) mred[wv] = x;
    }
    __syncthreads();
    float mloc = fmaxf(mred[0], mred[1]);

    // stage 2b: exp + local sum
    if (tid < 128) {
        float e = __expf(ul[tid] - mloc);
        el[tid] = e;
        float s = waveReduceSum(e);
        if (lane == 0) sred[wv] = s;
    }
    __syncthreads();

    // stage 3: context partial, lane owns d-float4
    const float4* base2 = (const float4*)enc + ((size_t)(b * T_ + chunk * 128)) * 64;
    float4 acc = {0.f, 0.f, 0.f, 0.f};
    #pragma unroll 8
    for (int i = 0; i < 32; i++) {
        int t = wv * 32 + i;
        float e = el[t];
        float4 ev = base2[(size_t)t * 64 + lane];
        acc.x += e * ev.x; acc.y += e * ev.y; acc.z += e * ev.z; acc.w += e * ev.w;
    }
    red[wv][lane] = acc;
    __syncthreads();
    if (tid < 64) {
        float4 s = red[0][tid];
        float4 a1 = red[1][tid], a2 = red[2][tid], a3 = red[3][tid];
        s.x += a1.x + a2.x + a3.x;
        s.y += a1.y + a2.y + a3.y;
        s.z += a1.z + a2.z + a3.z;
        s.w += a1.w + a2.w + a3.w;
        ((float4*)ctx_part)[(size_t)(b * 8 + chunk) * 64 + tid] = s;
    }
    if (tid == 0) {
        m_part[b * 8 + chunk] = mloc;
        s_part[b * 8 + chunk] = sred[0] + sred[1];
    }
}

// ---------------------------------------------------------------------------
// KB: combine partials -> context, scores, concat1.  grid=128 (per batch)
// ---------------------------------------------------------------------------
__global__ __launch_bounds__(256) void kb_combine(
    const float* __restrict__ u, const float* __restrict__ m_part,
    const float* __restrict__ s_part, const float* __restrict__ ctx_part,
    const float* __restrict__ attn_h,
    float* __restrict__ scores_out, float* __restrict__ ctx_out,
    float* __restrict__ concat1)
{
    const int b = blockIdx.x, tid = threadIdx.x;
    __shared__ float msh[8], ssh[8];
    if (tid < 8) {
        msh[tid] = m_part[b * 8 + tid];
        ssh[tid] = s_part[b * 8 + tid];
    }
    __syncthreads();

    float M = msh[0];
    #pragma unroll
    for (int c = 1; c < 8; c++) M = fmaxf(M, msh[c]);
    float S = 0.f;
    #pragma unroll
    for (int c = 0; c < 8; c++) S += ssh[c] * __expf(msh[c] - M);
    float invS = 1.f / S;

    // context for d = tid
    {
        float a = 0.f;
        #pragma unroll
        for (int c = 0; c < 8; c++)
            a += ctx_part[(size_t)(b * 8 + c) * 256 + tid] * __expf(msh[c] - M);
        a *= invS;
        ctx_out[b * 256 + tid] = a;
        concat1[b * 512 + tid] = a;
        concat1[b * 512 + 256 + tid] = attn_h[b * 256 + tid];
    }

    // normalized scores
    #pragma unroll
    for (int i = 0; i < 4; i++) {
        int t = i * 256 + tid;
        scores_out[b * T_ + t] = __expf(u[b * T_ + t] - M) * invS;
    }
}

// ---------------------------------------------------------------------------
// GEMM: part[z][m][n] = A_seg[m][k0:k0+KSZ] @ W_seg[n][k0:k0+KSZ]^T
// ---------------------------------------------------------------------------
__global__ __launch_bounds__(256) void gemm512_splitk(
    const float* __restrict__ A1, const float* __restrict__ W1,
    const float* __restrict__ A2, const float* __restrict__ W2,
    float* __restrict__ part, int N, int ksPerSeg)
{
    const int n0 = blockIdx.x * 64, m0 = blockIdx.y * 64;
    const int seg = blockIdx.z / ksPerSeg, ls = blockIdx.z % ksPerSeg;
    const int KSZ = 512 / ksPerSeg;
    const float* A = seg ? A2 : A1;
    const float* W = seg ? W2 : W1;
    const int k0 = ls * KSZ;

    __shared__ __align__(16) float As[32][68];
    __shared__ __align__(16) float Ws[32][68];

    const int tid = threadIdx.x;
    const int tm = tid & 15, tn = tid >> 4;
    const int rs = tid >> 3, qs = tid & 7;

    float acc[4][4] = {};

    for (int kt = 0; kt < KSZ; kt += 32) {
        #pragma unroll
        for (int it = 0; it < 2; it++) {
            int r = rs + it * 32;
            float4 av = *(const float4*)(A + (size_t)(m0 + r) * 512 + k0 + kt + qs * 4);
            As[qs * 4 + 0][r] = av.x; As[qs * 4 + 1][r] = av.y;
            As[qs * 4 + 2][r] = av.z; As[qs * 4 + 3][r] = av.w;
            float4 wv = *(const float4*)(W + (size_t)(n0 + r) * 512 + k0 + kt + qs * 4);
            Ws[qs * 4 + 0][r] = wv.x; Ws[qs * 4 + 1][r] = wv.y;
            Ws[qs * 4 + 2][r] = wv.z; Ws[qs * 4 + 3][r] = wv.w;
        }
        __syncthreads();
        #pragma unroll
        for (int kk = 0; kk < 32; kk++) {
            float4 a = *(const float4*)&As[kk][tm * 4];
            float4 w = *(const float4*)&Ws[kk][tn * 4];
            acc[0][0] += a.x * w.x; acc[0][1] += a.x * w.y; acc[0][2] += a.x * w.z; acc[0][3] += a.x * w.w;
            acc[1][0] += a.y * w.x; acc[1][1] += a.y * w.y; acc[1][2] += a.y * w.z; acc[1][3] += a.y * w.w;
            acc[2][0] += a.z * w.x; acc[2][1] += a.z * w.y; acc[2][2] += a.z * w.z; acc[2][3] += a.z * w.w;
            acc[3][0] += a.w * w.x; acc[3][1] += a.w * w.y; acc[3][2] += a.w * w.z; acc[3][3] += a.w * w.w;
        }
        __syncthreads();
    }

    float* pb = part + ((size_t)blockIdx.z * 128 + m0) * N + n0;
    #pragma unroll
    for (int i = 0; i < 4; i++) {
        float4 o = {acc[i][0], acc[i][1], acc[i][2], acc[i][3]};
        *(float4*)(pb + (size_t)(tm * 4 + i) * N + tn * 4) = o;
    }
}

// ---------------------------------------------------------------------------
// E_rnn: x = sum_z part[z] + bias     (N=512, 4 slices)
// ---------------------------------------------------------------------------
__global__ __launch_bounds__(256) void e_rnn(
    const float* __restrict__ part, const float* __restrict__ bias,
    float* __restrict__ x)
{
    const int idx = blockIdx.x * 256 + threadIdx.x;
    const int n = idx & 511;
    float a = bias[n];
    #pragma unroll
    for (int z = 0; z < 4; z++) a += part[(size_t)z * 65536 + idx];
    x[idx] = a;
}

// ---------------------------------------------------------------------------
// E_lstm1: gate reduce + LSTM cell + x_new = x_prev + h
// ---------------------------------------------------------------------------
__global__ __launch_bounds__(256) void e_lstm(
    const float* __restrict__ part,
    const float* __restrict__ bih, const float* __restrict__ bhh,
    const float* __restrict__ c_prev, const float* __restrict__ x_prev,
    float* __restrict__ h_out, float* __restrict__ c_out, float* __restrict__ x_new)
{
    const int idx = blockIdx.x * 256 + threadIdx.x;
    const int bb = idx >> 9, j = idx & 511;
    float gi = bih[j] + bhh[j];
    float gf = bih[512 + j] + bhh[512 + j];
    float gg = bih[1024 + j] + bhh[1024 + j];
    float go = bih[1536 + j] + bhh[1536 + j];
    #pragma unroll
    for (int z = 0; z < 4; z++) {
        const float* p = part + ((size_t)z * 128 + bb) * 2048;
        gi += p[j]; gf += p[512 + j]; gg += p[1024 + j]; go += p[1536 + j];
    }
    float c = sigmoidf_(gf) * c_prev[idx] + sigmoidf_(gi) * tanhf_(gg);
    float h = sigmoidf_(go) * tanhf_(c);
    h_out[idx] = h;
    c_out[idx] = c;
    x_new[idx] = x_prev[idx] + h;
}

// ---------------------------------------------------------------------------
// E_lstm2 + mel: grid=128 (per batch), block=512. x3 stays in LDS.
// ---------------------------------------------------------------------------
__global__ __launch_bounds__(512) void e_lstm2_mel(
    const float* __restrict__ part,
    const float* __restrict__ bih, const float* __restrict__ bhh,
    const float* __restrict__ c_prev, const float* __restrict__ x_prev,
    const float* __restrict__ mel_W, const int* __restrict__ r_ptr,
    float* __restrict__ h_out, float* __restrict__ c_out,
    float* __restrict__ mels)
{
    const int b = blockIdx.x, j = threadIdx.x;   // j < 512
    __shared__ __align__(16) float xs[512];

    const int idx = b * 512 + j;
    float gi = bih[j] + bhh[j];
    float gf = bih[512 + j] + bhh[512 + j];
    float gg = bih[1024 + j] + bhh[1024 + j];
    float go = bih[1536 + j] + bhh[1536 + j];
    #pragma unroll
    for (int z = 0; z < 4; z++) {
        const float* p = part + ((size_t)z * 128 + b) * 2048;
        gi += p[j]; gf += p[512 + j]; gg += p[1024 + j]; go += p[1536 + j];
    }
    float c = sigmoidf_(gf) * c_prev[idx] + sigmoidf_(gi) * tanhf_(gg);
    float h = sigmoidf_(go) * tanhf_(c);
    h_out[idx] = h;
    c_out[idx] = c;
    xs[j] = x_prev[idx] + h;
    __syncthreads();

    const int r = r_ptr[0];
    const int tot = 80 * r;
    for (int n = j; n < tot; n += 512) {
        int m = n / r, rr = n % r;
        const float4* w  = (const float4*)(mel_W + (size_t)(m * 20 + rr) * 512);
        const float4* xv = (const float4*)xs;
        float a = 0.f;
        #pragma unroll 8
        for (int k = 0; k < 128; k++) {
            float4 wv = w[k], vv = xv[k];
            a += wv.x * vv.x + wv.y * vv.y + wv.z * vv.z + wv.w * vv.w;
        }
        mels[(size_t)b * tot + n] = a;
    }
}

// ---------------------------------------------------------------------------
extern "C" void kernel_launch(void* const* d_in, const int* in_sizes, int n_in,
                              void* d_out, int out_size, void* d_ws, size_t ws_size,
                              hipStream_t stream)
{
    const float* enc   = (const float*)d_in[0];
    const float* encp  = (const float*)d_in[1];
    const float* pre   = (const float*)d_in[2];
    const float* ah_in = (const float*)d_in[3];
    const float* r1h   = (const float*)d_in[4];
    const float* r2h   = (const float*)d_in[5];
    const float* r1c   = (const float*)d_in[6];
    const float* r2c   = (const float*)d_in[7];
    const float* cvec  = (const float*)d_in[8];
    const float* fc1W  = (const float*)d_in[9];
    const float* fc1b  = (const float*)d_in[10];
    const float* fc2W  = (const float*)d_in[11];
    const float* fc2b  = (const float*)d_in[12];
    const float* attnW = (const float*)d_in[13];
    const float* attnv = (const float*)d_in[14];
    const float* gWih  = (const float*)d_in[15];
    const float* gWhh  = (const float*)d_in[16];
    const float* gbih  = (const float*)d_in[17];
    const float* gbhh  = (const float*)d_in[18];
    const float* rinW  = (const float*)d_in[19];
    const float* rinb  = (const float*)d_in[20];
    const float* l1Wih = (const float*)d_in[21];
    const float* l1Whh = (const float*)d_in[22];
    const float* l1bih = (const float*)d_in[23];
    const float* l1bhh = (const float*)d_in[24];
    const float* l2Wih = (const float*)d_in[25];
    const float* l2Whh = (const float*)d_in[26];
    const float* l2bih = (const float*)d_in[27];
    const float* l2bhh = (const float*)d_in[28];
    const float* melW  = (const float*)d_in[29];
    const int*   rp    = (const int*)d_in[30];

    float* out = (float*)d_out;
    float* o_mels  = out + 0;        // 128*80*2
    float* o_scor  = out + 20480;    // 128*1024
    float* o_attnh = out + 151552;   // 128*256
    float* o_r1h   = out + 184320;   // 128*512
    float* o_r2h   = out + 249856;
    float* o_r1c   = out + 315392;
    float* o_r2c   = out + 380928;
    float* o_ctx   = out + 446464;   // 128*256

    float* ws     = (float*)d_ws;
    float* w_q    = ws + 0;          // 32768
    float* w_u    = ws + 32768;      // 131072
    float* w_m    = ws + 163840;     // 1024
    float* w_s    = ws + 164864;     // 1024
    float* w_ctxp = ws + 165888;     // 8*128*256 = 262144
    float* w_cat1 = ws + 428032;     // 65536
    float* w_x    = ws + 493568;     // 65536
    float* w_x2   = ws + 559104;     // 65536
    float* w_part = ws + 624640;     // 4*128*2048 = 1048576

    hipLaunchKernelGGL(k1_fused, dim3(64), dim3(256), 0, stream,
                       pre, ah_in, cvec, fc1W, fc1b, fc2W, fc2b,
                       gWih, gWhh, gbih, gbhh, attnW, o_attnh, w_q);

    hipLaunchKernelGGL(ka_attn, dim3(1024), dim3(256), 0, stream,
                       encp, enc, w_q, attnv, w_u, w_ctxp, w_m, w_s);

    hipLaunchKernelGGL(kb_combine, dim3(128), dim3(256), 0, stream,
                       w_u, w_m, w_s, w_ctxp, o_attnh, o_scor, o_ctx, w_cat1);

    // rnn_in: K=512, 4 k-slices
    hipLaunchKernelGGL(gemm512_splitk, dim3(8, 2, 4), dim3(256), 0, stream,
                       w_cat1, rinW, w_cat1, rinW, w_part, 512, 4);
    hipLaunchKernelGGL(e_rnn, dim3(256), dim3(256), 0, stream, w_part, rinb, w_x);

    // LSTM 1
    hipLaunchKernelGGL(gemm512_splitk, dim3(32, 2, 4), dim3(256), 0, stream,
                       w_x, l1Wih, r1h, l1Whh, w_part, 2048, 2);
    hipLaunchKernelGGL(e_lstm, dim3(256), dim3(256), 0, stream,
                       w_part, l1bih, l1bhh, r1c, w_x, o_r1h, o_r1c, w_x2);

    // LSTM 2 + mel
    hipLaunchKernelGGL(gemm512_splitk, dim3(32, 2, 4), dim3(256), 0, stream,
                       w_x2, l2Wih, r2h, l2Whh, w_part, 2048, 2);
    hipLaunchKernelGGL(e_lstm2_mel, dim3(128), dim3(512), 0, stream,
                       w_part, l2bih, l2bhh, r2c, w_x2, melW, rp,
                       o_r2h, o_r2c, o_mels);
}

// Round 4
// 155.074 us; speedup vs baseline: 1.2229x; 1.2229x over previous
//
#include <hip/hip_runtime.h>
#include <math.h>

#define B_   128
#define T_   1024
#define D_   256
#define L_   512

__device__ __forceinline__ float sigmoidf_(float x) {
    return 1.f / (1.f + __expf(-x));
}
__device__ __forceinline__ float tanhf_(float x) {
    x = fminf(fmaxf(x, -15.f), 15.f);
    float e = __expf(2.f * x);
    return (e - 1.f) / (e + 1.f);
}
// tanh(x) = 1 - 2/(exp(2x)+1); exact identity, v_exp + v_rcp, no clamp needed
// (exp->inf => rcp->0 => 1; exp->0 => -1)
__device__ __forceinline__ float tanh_fast(float x) {
    float e = __expf(2.f * x);
    return 1.f - 2.f * __builtin_amdgcn_rcpf(e + 1.f);
}
__device__ __forceinline__ float waveReduceSum(float v) {
    #pragma unroll
    for (int o = 32; o > 0; o >>= 1) v += __shfl_xor(v, o, 64);
    return v;
}
__device__ __forceinline__ float waveReduceMax(float v) {
    #pragma unroll
    for (int o = 32; o > 0; o >>= 1) v = fmaxf(v, __shfl_xor(v, o, 64));
    return v;
}

// ---------------------------------------------------------------------------
// K1a: prenet per batch.  grid=128, block=256
// ---------------------------------------------------------------------------
__global__ __launch_bounds__(256) void k1a_prenet(
    const float* __restrict__ prenet_in,
    const float* __restrict__ fc1_W, const float* __restrict__ fc1_b,
    const float* __restrict__ fc2_W, const float* __restrict__ fc2_b,
    float* __restrict__ p2_out)
{
    const int b = blockIdx.x, t = threadIdx.x;
    __shared__ __align__(16) float pin[80];
    __shared__ __align__(16) float p1[256];

    if (t < 80) pin[t] = prenet_in[b * 80 + t];
    __syncthreads();

    {
        float a = fc1_b[t];
        const float4* w  = (const float4*)(fc1_W + t * 80);
        const float4* xv = (const float4*)pin;
        #pragma unroll
        for (int k = 0; k < 20; k++) {
            float4 wv = w[k], v = xv[k];
            a += v.x * wv.x + v.y * wv.y + v.z * wv.z + v.w * wv.w;
        }
        p1[t] = fmaxf(a, 0.f);
    }
    __syncthreads();

    if (t < 128) {
        float a = fc2_b[t];
        const float4* w  = (const float4*)(fc2_W + t * 256);
        const float4* xv = (const float4*)p1;
        #pragma unroll 8
        for (int k = 0; k < 64; k++) {
            float4 wv = w[k], v = xv[k];
            a += v.x * wv.x + v.y * wv.y + v.z * wv.z + v.w * wv.w;
        }
        p2_out[b * 128 + t] = fmaxf(a, 0.f);
    }
}

// ---------------------------------------------------------------------------
// K1b: GRU gate GEMVs.  grid = (3 j-tiles, 64 batch-pairs), block = 256.
// ---------------------------------------------------------------------------
__global__ __launch_bounds__(256) void k1b_gru_gemv(
    const float* __restrict__ context_vec, const float* __restrict__ p2,
    const float* __restrict__ attn_hidden,
    const float* __restrict__ gru_Wih, const float* __restrict__ gru_Whh,
    const float* __restrict__ gru_bih, const float* __restrict__ gru_bhh,
    float* __restrict__ gi_out, float* __restrict__ gh_out)
{
    const int t = threadIdx.x;
    const int j = blockIdx.x * 256 + t;
    const int b0 = blockIdx.y * 2;

    __shared__ __align__(16) float xs[2][384];
    __shared__ __align__(16) float hs[2][256];

    for (int i = t; i < 768; i += 256) {
        int bb = i / 384, k = i % 384;
        xs[bb][k] = (k < 256) ? context_vec[(b0 + bb) * 256 + k]
                              : p2[(b0 + bb) * 128 + (k - 256)];
    }
    for (int i = t; i < 512; i += 256) {
        hs[i / 256][i % 256] = attn_hidden[(b0 + i / 256) * 256 + (i % 256)];
    }
    __syncthreads();

    {
        float a0 = gru_bih[j], a1 = a0;
        const float4* w  = (const float4*)(gru_Wih + (size_t)j * 384);
        const float4* x0 = (const float4*)xs[0];
        const float4* x1 = (const float4*)xs[1];
        #pragma unroll 8
        for (int k = 0; k < 96; k++) {
            float4 wv = w[k], v0 = x0[k], v1 = x1[k];
            a0 += v0.x * wv.x + v0.y * wv.y + v0.z * wv.z + v0.w * wv.w;
            a1 += v1.x * wv.x + v1.y * wv.y + v1.z * wv.z + v1.w * wv.w;
        }
        gi_out[(size_t)(b0 + 0) * 768 + j] = a0;
        gi_out[(size_t)(b0 + 1) * 768 + j] = a1;
    }
    {
        float a0 = gru_bhh[j], a1 = a0;
        const float4* w  = (const float4*)(gru_Whh + (size_t)j * 256);
        const float4* x0 = (const float4*)hs[0];
        const float4* x1 = (const float4*)hs[1];
        #pragma unroll 8
        for (int k = 0; k < 64; k++) {
            float4 wv = w[k], v0 = x0[k], v1 = x1[k];
            a0 += v0.x * wv.x + v0.y * wv.y + v0.z * wv.z + v0.w * wv.w;
            a1 += v1.x * wv.x + v1.y * wv.y + v1.z * wv.z + v1.w * wv.w;
        }
        gh_out[(size_t)(b0 + 0) * 768 + j] = a0;
        gh_out[(size_t)(b0 + 1) * 768 + j] = a1;
    }
}

// ---------------------------------------------------------------------------
// K1c: GRU gates + q = attn_h @ attn_W.T.   grid=128, block=256
// ---------------------------------------------------------------------------
__global__ __launch_bounds__(256) void k1c_gates_q(
    const float* __restrict__ gi, const float* __restrict__ gh,
    const float* __restrict__ attn_hidden, const float* __restrict__ attn_W,
    float* __restrict__ attn_h_out, float* __restrict__ q_out)
{
    const int b = blockIdx.x, t = threadIdx.x;
    __shared__ __align__(16) float ahn[256];

    {
        float hp = attn_hidden[b * 256 + t];
        float rg = sigmoidf_(gi[(size_t)b * 768 + t]       + gh[(size_t)b * 768 + t]);
        float zg = sigmoidf_(gi[(size_t)b * 768 + 256 + t] + gh[(size_t)b * 768 + 256 + t]);
        float ng = tanhf_(gi[(size_t)b * 768 + 512 + t] + rg * gh[(size_t)b * 768 + 512 + t]);
        float h  = (1.f - zg) * ng + zg * hp;
        ahn[t] = h;
        attn_h_out[b * 256 + t] = h;
    }
    __syncthreads();

    {
        float a = 0.f;
        const float4* w  = (const float4*)(attn_W + (size_t)t * 256);
        const float4* xv = (const float4*)ahn;
        #pragma unroll 8
        for (int k = 0; k < 64; k++) {
            float4 wv = w[k], v = xv[k];
            a += v.x * wv.x + v.y * wv.y + v.z * wv.z + v.w * wv.w;
        }
        q_out[b * 256 + t] = a;
    }
}

// ---------------------------------------------------------------------------
// KA: fused attention pass.  grid = B*16 chunks of 64 t, block=256 (4 waves).
// stage1: 16-lane group owns one t; lanes cover 64 d/iter, 4 iters.
//         4 t's reduced simultaneously per wave with a 4-deep shfl chain.
// stage2: wave 0 does chunk-local max/exp/sum (64 entries).
// stage3: wave wv accumulates ctx partial over its 16 t's.
// ---------------------------------------------------------------------------
__global__ __launch_bounds__(256) void ka_attn(
    const float* __restrict__ enc_proj, const float* __restrict__ enc,
    const float* __restrict__ q, const float* __restrict__ v,
    float* __restrict__ u_out, float* __restrict__ ctx_part,
    float* __restrict__ m_part, float* __restrict__ s_part)
{
    const int b     = blockIdx.x >> 4;
    const int chunk = blockIdx.x & 15;
    const int tid   = threadIdx.x;
    const int lane  = tid & 63;
    const int wv    = tid >> 6;    // 0..3
    const int g     = lane >> 4;   // 16-lane group 0..3
    const int gl    = lane & 15;

    __shared__ float ul[64];
    __shared__ float el[64];
    __shared__ __align__(16) float4 red[4][64];

    const int t0 = chunk * 64;

    // per-lane copies of q,v covering all 4 d-chunks of 64
    float4 qv[4], vv[4];
    #pragma unroll
    for (int c = 0; c < 4; c++) {
        qv[c] = ((const float4*)(q + b * 256))[c * 16 + gl];
        vv[c] = ((const float4*)v)[c * 16 + gl];
    }

    // ---- stage 1 ----
    const float* ebase = enc_proj + ((size_t)(b * T_ + t0)) * 256;
    #pragma unroll
    for (int pass = 0; pass < 4; pass++) {
        const int t = wv * 16 + pass * 4 + g;
        const float4* row = (const float4*)(ebase + (size_t)t * 256);
        float s = 0.f;
        #pragma unroll
        for (int c = 0; c < 4; c++) {
            float4 pj = row[c * 16 + gl];
            s += tanh_fast(pj.x + qv[c].x) * vv[c].x
               + tanh_fast(pj.y + qv[c].y) * vv[c].y
               + tanh_fast(pj.z + qv[c].z) * vv[c].z
               + tanh_fast(pj.w + qv[c].w) * vv[c].w;
        }
        // reduce within 16-lane group (all 4 groups in parallel)
        s += __shfl_xor(s, 1, 64);
        s += __shfl_xor(s, 2, 64);
        s += __shfl_xor(s, 4, 64);
        s += __shfl_xor(s, 8, 64);
        if (gl == 0) ul[t] = s;
    }
    __syncthreads();

    // ---- stage 2 (wave 0 only) ----
    if (wv == 0) {
        float x = ul[lane];
        u_out[b * T_ + t0 + lane] = x;
        float mx = waveReduceMax(x);
        float e = __expf(x - mx);
        el[lane] = e;
        float ss = waveReduceSum(e);
        if (lane == 0) {
            m_part[b * 16 + chunk] = mx;
            s_part[b * 16 + chunk] = ss;
        }
    }
    __syncthreads();

    // ---- stage 3 ----
    const float4* base2 = (const float4*)(enc + ((size_t)(b * T_ + t0)) * 256);
    float4 acc0 = {0.f, 0.f, 0.f, 0.f}, acc1 = {0.f, 0.f, 0.f, 0.f};
    #pragma unroll
    for (int i = 0; i < 16; i += 2) {
        int t = wv * 16 + i;
        float e0 = el[t], e1 = el[t + 1];
        float4 v0 = base2[(size_t)t * 64 + lane];
        float4 v1 = base2[(size_t)(t + 1) * 64 + lane];
        acc0.x += e0 * v0.x; acc0.y += e0 * v0.y; acc0.z += e0 * v0.z; acc0.w += e0 * v0.w;
        acc1.x += e1 * v1.x; acc1.y += e1 * v1.y; acc1.z += e1 * v1.z; acc1.w += e1 * v1.w;
    }
    acc0.x += acc1.x; acc0.y += acc1.y; acc0.z += acc1.z; acc0.w += acc1.w;
    red[wv][lane] = acc0;
    __syncthreads();
    if (tid < 64) {
        float4 s = red[0][tid];
        float4 a1 = red[1][tid], a2 = red[2][tid], a3 = red[3][tid];
        s.x += a1.x + a2.x + a3.x;
        s.y += a1.y + a2.y + a3.y;
        s.z += a1.z + a2.z + a3.z;
        s.w += a1.w + a2.w + a3.w;
        ((float4*)ctx_part)[(size_t)(b * 16 + chunk) * 64 + tid] = s;
    }
}

// ---------------------------------------------------------------------------
// KB: combine 16 partials -> context, scores, concat1.  grid=128 (per batch)
// ---------------------------------------------------------------------------
__global__ __launch_bounds__(256) void kb_combine(
    const float* __restrict__ u, const float* __restrict__ m_part,
    const float* __restrict__ s_part, const float* __restrict__ ctx_part,
    const float* __restrict__ attn_h,
    float* __restrict__ scores_out, float* __restrict__ ctx_out,
    float* __restrict__ concat1)
{
    const int b = blockIdx.x, tid = threadIdx.x;
    __shared__ float msh[16], ssh[16];
    if (tid < 16) {
        msh[tid] = m_part[b * 16 + tid];
        ssh[tid] = s_part[b * 16 + tid];
    }
    __syncthreads();

    float M = msh[0];
    #pragma unroll
    for (int c = 1; c < 16; c++) M = fmaxf(M, msh[c]);
    float S = 0.f;
    #pragma unroll
    for (int c = 0; c < 16; c++) S += ssh[c] * __expf(msh[c] - M);
    float invS = 1.f / S;

    {
        float a = 0.f;
        #pragma unroll
        for (int c = 0; c < 16; c++)
            a += ctx_part[(size_t)(b * 16 + c) * 256 + tid] * __expf(msh[c] - M);
        a *= invS;
        ctx_out[b * 256 + tid] = a;
        concat1[b * 512 + tid] = a;
        concat1[b * 512 + 256 + tid] = attn_h[b * 256 + tid];
    }

    #pragma unroll
    for (int i = 0; i < 4; i++) {
        int t = i * 256 + tid;
        scores_out[b * T_ + t] = __expf(u[b * T_ + t] - M) * invS;
    }
}

// ---------------------------------------------------------------------------
// GEMM: part[z][m][n] = A_seg[m][k0:k0+KSZ] @ W_seg[n][k0:k0+KSZ]^T
// ---------------------------------------------------------------------------
__global__ __launch_bounds__(256) void gemm512_splitk(
    const float* __restrict__ A1, const float* __restrict__ W1,
    const float* __restrict__ A2, const float* __restrict__ W2,
    float* __restrict__ part, int N, int ksPerSeg)
{
    const int n0 = blockIdx.x * 64, m0 = blockIdx.y * 64;
    const int seg = blockIdx.z / ksPerSeg, ls = blockIdx.z % ksPerSeg;
    const int KSZ = 512 / ksPerSeg;
    const float* A = seg ? A2 : A1;
    const float* W = seg ? W2 : W1;
    const int k0 = ls * KSZ;

    __shared__ __align__(16) float As[32][68];
    __shared__ __align__(16) float Ws[32][68];

    const int tid = threadIdx.x;
    const int tm = tid & 15, tn = tid >> 4;
    const int rs = tid >> 3, qs = tid & 7;

    float acc[4][4] = {};

    for (int kt = 0; kt < KSZ; kt += 32) {
        #pragma unroll
        for (int it = 0; it < 2; it++) {
            int r = rs + it * 32;
            float4 av = *(const float4*)(A + (size_t)(m0 + r) * 512 + k0 + kt + qs * 4);
            As[qs * 4 + 0][r] = av.x; As[qs * 4 + 1][r] = av.y;
            As[qs * 4 + 2][r] = av.z; As[qs * 4 + 3][r] = av.w;
            float4 wv = *(const float4*)(W + (size_t)(n0 + r) * 512 + k0 + kt + qs * 4);
            Ws[qs * 4 + 0][r] = wv.x; Ws[qs * 4 + 1][r] = wv.y;
            Ws[qs * 4 + 2][r] = wv.z; Ws[qs * 4 + 3][r] = wv.w;
        }
        __syncthreads();
        #pragma unroll
        for (int kk = 0; kk < 32; kk++) {
            float4 a = *(const float4*)&As[kk][tm * 4];
            float4 w = *(const float4*)&Ws[kk][tn * 4];
            acc[0][0] += a.x * w.x; acc[0][1] += a.x * w.y; acc[0][2] += a.x * w.z; acc[0][3] += a.x * w.w;
            acc[1][0] += a.y * w.x; acc[1][1] += a.y * w.y; acc[1][2] += a.y * w.z; acc[1][3] += a.y * w.w;
            acc[2][0] += a.z * w.x; acc[2][1] += a.z * w.y; acc[2][2] += a.z * w.z; acc[2][3] += a.z * w.w;
            acc[3][0] += a.w * w.x; acc[3][1] += a.w * w.y; acc[3][2] += a.w * w.z; acc[3][3] += a.w * w.w;
        }
        __syncthreads();
    }

    float* pb = part + ((size_t)blockIdx.z * 128 + m0) * N + n0;
    #pragma unroll
    for (int i = 0; i < 4; i++) {
        float4 o = {acc[i][0], acc[i][1], acc[i][2], acc[i][3]};
        *(float4*)(pb + (size_t)(tm * 4 + i) * N + tn * 4) = o;
    }
}

// ---------------------------------------------------------------------------
__global__ __launch_bounds__(256) void e_rnn(
    const float* __restrict__ part, const float* __restrict__ bias,
    float* __restrict__ x)
{
    const int idx = blockIdx.x * 256 + threadIdx.x;
    const int n = idx & 511;
    float a = bias[n];
    #pragma unroll
    for (int z = 0; z < 4; z++) a += part[(size_t)z * 65536 + idx];
    x[idx] = a;
}

// ---------------------------------------------------------------------------
__global__ __launch_bounds__(256) void e_lstm(
    const float* __restrict__ part,
    const float* __restrict__ bih, const float* __restrict__ bhh,
    const float* __restrict__ c_prev, const float* __restrict__ x_prev,
    float* __restrict__ h_out, float* __restrict__ c_out, float* __restrict__ x_new)
{
    const int idx = blockIdx.x * 256 + threadIdx.x;
    const int bb = idx >> 9, j = idx & 511;
    float gi = bih[j] + bhh[j];
    float gf = bih[512 + j] + bhh[512 + j];
    float gg = bih[1024 + j] + bhh[1024 + j];
    float go = bih[1536 + j] + bhh[1536 + j];
    #pragma unroll
    for (int z = 0; z < 4; z++) {
        const float* p = part + ((size_t)z * 128 + bb) * 2048;
        gi += p[j]; gf += p[512 + j]; gg += p[1024 + j]; go += p[1536 + j];
    }
    float c = sigmoidf_(gf) * c_prev[idx] + sigmoidf_(gi) * tanhf_(gg);
    float h = sigmoidf_(go) * tanhf_(c);
    h_out[idx] = h;
    c_out[idx] = c;
    x_new[idx] = x_prev[idx] + h;
}

// ---------------------------------------------------------------------------
__global__ __launch_bounds__(512) void e_lstm2_mel(
    const float* __restrict__ part,
    const float* __restrict__ bih, const float* __restrict__ bhh,
    const float* __restrict__ c_prev, const float* __restrict__ x_prev,
    const float* __restrict__ mel_W, const int* __restrict__ r_ptr,
    float* __restrict__ h_out, float* __restrict__ c_out,
    float* __restrict__ mels)
{
    const int b = blockIdx.x, j = threadIdx.x;
    __shared__ __align__(16) float xs[512];

    const int idx = b * 512 + j;
    float gi = bih[j] + bhh[j];
    float gf = bih[512 + j] + bhh[512 + j];
    float gg = bih[1024 + j] + bhh[1024 + j];
    float go = bih[1536 + j] + bhh[1536 + j];
    #pragma unroll
    for (int z = 0; z < 4; z++) {
        const float* p = part + ((size_t)z * 128 + b) * 2048;
        gi += p[j]; gf += p[512 + j]; gg += p[1024 + j]; go += p[1536 + j];
    }
    float c = sigmoidf_(gf) * c_prev[idx] + sigmoidf_(gi) * tanhf_(gg);
    float h = sigmoidf_(go) * tanhf_(c);
    h_out[idx] = h;
    c_out[idx] = c;
    xs[j] = x_prev[idx] + h;
    __syncthreads();

    const int r = r_ptr[0];
    const int tot = 80 * r;
    for (int n = j; n < tot; n += 512) {
        int m = n / r, rr = n % r;
        const float4* w  = (const float4*)(mel_W + (size_t)(m * 20 + rr) * 512);
        const float4* xv = (const float4*)xs;
        float a = 0.f;
        #pragma unroll 8
        for (int k = 0; k < 128; k++) {
            float4 wv = w[k], vv = xv[k];
            a += wv.x * vv.x + wv.y * vv.y + wv.z * vv.z + wv.w * vv.w;
        }
        mels[(size_t)b * tot + n] = a;
    }
}

// ---------------------------------------------------------------------------
extern "C" void kernel_launch(void* const* d_in, const int* in_sizes, int n_in,
                              void* d_out, int out_size, void* d_ws, size_t ws_size,
                              hipStream_t stream)
{
    const float* enc   = (const float*)d_in[0];
    const float* encp  = (const float*)d_in[1];
    const float* pre   = (const float*)d_in[2];
    const float* ah_in = (const float*)d_in[3];
    const float* r1h   = (const float*)d_in[4];
    const float* r2h   = (const float*)d_in[5];
    const float* r1c   = (const float*)d_in[6];
    const float* r2c   = (const float*)d_in[7];
    const float* cvec  = (const float*)d_in[8];
    const float* fc1W  = (const float*)d_in[9];
    const float* fc1b  = (const float*)d_in[10];
    const float* fc2W  = (const float*)d_in[11];
    const float* fc2b  = (const float*)d_in[12];
    const float* attnW = (const float*)d_in[13];
    const float* attnv = (const float*)d_in[14];
    const float* gWih  = (const float*)d_in[15];
    const float* gWhh  = (const float*)d_in[16];
    const float* gbih  = (const float*)d_in[17];
    const float* gbhh  = (const float*)d_in[18];
    const float* rinW  = (const float*)d_in[19];
    const float* rinb  = (const float*)d_in[20];
    const float* l1Wih = (const float*)d_in[21];
    const float* l1Whh = (const float*)d_in[22];
    const float* l1bih = (const float*)d_in[23];
    const float* l1bhh = (const float*)d_in[24];
    const float* l2Wih = (const float*)d_in[25];
    const float* l2Whh = (const float*)d_in[26];
    const float* l2bih = (const float*)d_in[27];
    const float* l2bhh = (const float*)d_in[28];
    const float* melW  = (const float*)d_in[29];
    const int*   rp    = (const int*)d_in[30];

    float* out = (float*)d_out;
    float* o_mels  = out + 0;        // 128*80*2
    float* o_scor  = out + 20480;    // 128*1024
    float* o_attnh = out + 151552;   // 128*256
    float* o_r1h   = out + 184320;   // 128*512
    float* o_r2h   = out + 249856;
    float* o_r1c   = out + 315392;
    float* o_r2c   = out + 380928;
    float* o_ctx   = out + 446464;   // 128*256

    float* ws     = (float*)d_ws;
    float* w_q    = ws + 0;          // 32768
    float* w_u    = ws + 32768;      // 131072
    float* w_m    = ws + 163840;     // 2048
    float* w_s    = ws + 165888;     // 2048
    float* w_ctxp = ws + 167936;     // 16*128*256 = 524288
    float* w_cat1 = ws + 692224;     // 65536
    float* w_x    = ws + 757760;     // 65536
    float* w_x2   = ws + 823296;     // 65536
    float* w_part = ws + 888832;     // 4*128*2048 = 1048576

    // front-end scratch reuses the w_part region (free until the GEMM phase)
    float* w_p2 = w_part;            // 128*128
    float* w_gi = w_part + 16384;    // 128*768
    float* w_gh = w_part + 114688;   // 128*768

    hipLaunchKernelGGL(k1a_prenet, dim3(128), dim3(256), 0, stream,
                       pre, fc1W, fc1b, fc2W, fc2b, w_p2);

    hipLaunchKernelGGL(k1b_gru_gemv, dim3(3, 64), dim3(256), 0, stream,
                       cvec, w_p2, ah_in, gWih, gWhh, gbih, gbhh, w_gi, w_gh);

    hipLaunchKernelGGL(k1c_gates_q, dim3(128), dim3(256), 0, stream,
                       w_gi, w_gh, ah_in, attnW, o_attnh, w_q);

    hipLaunchKernelGGL(ka_attn, dim3(2048), dim3(256), 0, stream,
                       encp, enc, w_q, attnv, w_u, w_ctxp, w_m, w_s);

    hipLaunchKernelGGL(kb_combine, dim3(128), dim3(256), 0, stream,
                       w_u, w_m, w_s, w_ctxp, o_attnh, o_scor, o_ctx, w_cat1);

    // rnn_in: K=512, 4 k-slices
    hipLaunchKernelGGL(gemm512_splitk, dim3(8, 2, 4), dim3(256), 0, stream,
                       w_cat1, rinW, w_cat1, rinW, w_part, 512, 4);
    hipLaunchKernelGGL(e_rnn, dim3(256), dim3(256), 0, stream, w_part, rinb, w_x);

    // LSTM 1
    hipLaunchKernelGGL(gemm512_splitk, dim3(32, 2, 4), dim3(256), 0, stream,
                       w_x, l1Wih, r1h, l1Whh, w_part, 2048, 2);
    hipLaunchKernelGGL(e_lstm, dim3(256), dim3(256), 0, stream,
                       w_part, l1bih, l1bhh, r1c, w_x, o_r1h, o_r1c, w_x2);

    // LSTM 2 + mel
    hipLaunchKernelGGL(gemm512_splitk, dim3(32, 2, 4), dim3(256), 0, stream,
                       w_x2, l2Wih, r2h, l2Whh, w_part, 2048, 2);
    hipLaunchKernelGGL(e_lstm2_mel, dim3(128), dim3(512), 0, stream,
                       w_part, l2bih, l2bhh, r2c, w_x2, melW, rp,
                       o_r2h, o_r2c, o_mels);
}

// Round 5
// 154.787 us; speedup vs baseline: 1.2251x; 1.0019x over previous
//
#include <hip/hip_runtime.h>
#include <math.h>

#define B_   128
#define T_   1024
#define D_   256
#define L_   512

__device__ __forceinline__ float sigmoidf_(float x) {
    return 1.f / (1.f + __expf(-x));
}
__device__ __forceinline__ float tanhf_(float x) {
    x = fminf(fmaxf(x, -15.f), 15.f);
    float e = __expf(2.f * x);
    return (e - 1.f) / (e + 1.f);
}
// tanh(x) = 1 - 2/(exp(2x)+1); exact identity, v_exp + v_rcp
__device__ __forceinline__ float tanh_fast(float x) {
    float e = __expf(2.f * x);
    return 1.f - 2.f * __builtin_amdgcn_rcpf(e + 1.f);
}
__device__ __forceinline__ float waveReduceSum(float v) {
    #pragma unroll
    for (int o = 32; o > 0; o >>= 1) v += __shfl_xor(v, o, 64);
    return v;
}

// ---------------------------------------------------------------------------
// K1a: prenet per batch.  grid=128, block=256
// ---------------------------------------------------------------------------
__global__ __launch_bounds__(256) void k1a_prenet(
    const float* __restrict__ prenet_in,
    const float* __restrict__ fc1_W, const float* __restrict__ fc1_b,
    const float* __restrict__ fc2_W, const float* __restrict__ fc2_b,
    float* __restrict__ p2_out)
{
    const int b = blockIdx.x, t = threadIdx.x;
    __shared__ __align__(16) float pin[80];
    __shared__ __align__(16) float p1[256];

    if (t < 80) pin[t] = prenet_in[b * 80 + t];
    __syncthreads();

    {
        float a = fc1_b[t];
        const float4* w  = (const float4*)(fc1_W + t * 80);
        const float4* xv = (const float4*)pin;
        #pragma unroll
        for (int k = 0; k < 20; k++) {
            float4 wv = w[k], v = xv[k];
            a += v.x * wv.x + v.y * wv.y + v.z * wv.z + v.w * wv.w;
        }
        p1[t] = fmaxf(a, 0.f);
    }
    __syncthreads();

    if (t < 128) {
        float a = fc2_b[t];
        const float4* w  = (const float4*)(fc2_W + t * 256);
        const float4* xv = (const float4*)p1;
        #pragma unroll 8
        for (int k = 0; k < 64; k++) {
            float4 wv = w[k], v = xv[k];
            a += v.x * wv.x + v.y * wv.y + v.z * wv.z + v.w * wv.w;
        }
        p2_out[b * 128 + t] = fmaxf(a, 0.f);
    }
}

// ---------------------------------------------------------------------------
// K1b: GRU gate GEMVs.  grid = (3 j-tiles, 64 batch-pairs), block = 256.
// ---------------------------------------------------------------------------
__global__ __launch_bounds__(256) void k1b_gru_gemv(
    const float* __restrict__ context_vec, const float* __restrict__ p2,
    const float* __restrict__ attn_hidden,
    const float* __restrict__ gru_Wih, const float* __restrict__ gru_Whh,
    const float* __restrict__ gru_bih, const float* __restrict__ gru_bhh,
    float* __restrict__ gi_out, float* __restrict__ gh_out)
{
    const int t = threadIdx.x;
    const int j = blockIdx.x * 256 + t;
    const int b0 = blockIdx.y * 2;

    __shared__ __align__(16) float xs[2][384];
    __shared__ __align__(16) float hs[2][256];

    for (int i = t; i < 768; i += 256) {
        int bb = i / 384, k = i % 384;
        xs[bb][k] = (k < 256) ? context_vec[(b0 + bb) * 256 + k]
                              : p2[(b0 + bb) * 128 + (k - 256)];
    }
    for (int i = t; i < 512; i += 256) {
        hs[i / 256][i % 256] = attn_hidden[(b0 + i / 256) * 256 + (i % 256)];
    }
    __syncthreads();

    {
        float a0 = gru_bih[j], a1 = a0;
        const float4* w  = (const float4*)(gru_Wih + (size_t)j * 384);
        const float4* x0 = (const float4*)xs[0];
        const float4* x1 = (const float4*)xs[1];
        #pragma unroll 8
        for (int k = 0; k < 96; k++) {
            float4 wv = w[k], v0 = x0[k], v1 = x1[k];
            a0 += v0.x * wv.x + v0.y * wv.y + v0.z * wv.z + v0.w * wv.w;
            a1 += v1.x * wv.x + v1.y * wv.y + v1.z * wv.z + v1.w * wv.w;
        }
        gi_out[(size_t)(b0 + 0) * 768 + j] = a0;
        gi_out[(size_t)(b0 + 1) * 768 + j] = a1;
    }
    {
        float a0 = gru_bhh[j], a1 = a0;
        const float4* w  = (const float4*)(gru_Whh + (size_t)j * 256);
        const float4* x0 = (const float4*)hs[0];
        const float4* x1 = (const float4*)hs[1];
        #pragma unroll 8
        for (int k = 0; k < 64; k++) {
            float4 wv = w[k], v0 = x0[k], v1 = x1[k];
            a0 += v0.x * wv.x + v0.y * wv.y + v0.z * wv.z + v0.w * wv.w;
            a1 += v1.x * wv.x + v1.y * wv.y + v1.z * wv.z + v1.w * wv.w;
        }
        gh_out[(size_t)(b0 + 0) * 768 + j] = a0;
        gh_out[(size_t)(b0 + 1) * 768 + j] = a1;
    }
}

// ---------------------------------------------------------------------------
// K1c: GRU gates + q = attn_h @ attn_W.T.   grid=128, block=256
// ---------------------------------------------------------------------------
__global__ __launch_bounds__(256) void k1c_gates_q(
    const float* __restrict__ gi, const float* __restrict__ gh,
    const float* __restrict__ attn_hidden, const float* __restrict__ attn_W,
    float* __restrict__ attn_h_out, float* __restrict__ q_out)
{
    const int b = blockIdx.x, t = threadIdx.x;
    __shared__ __align__(16) float ahn[256];

    {
        float hp = attn_hidden[b * 256 + t];
        float rg = sigmoidf_(gi[(size_t)b * 768 + t]       + gh[(size_t)b * 768 + t]);
        float zg = sigmoidf_(gi[(size_t)b * 768 + 256 + t] + gh[(size_t)b * 768 + 256 + t]);
        float ng = tanhf_(gi[(size_t)b * 768 + 512 + t] + rg * gh[(size_t)b * 768 + 512 + t]);
        float h  = (1.f - zg) * ng + zg * hp;
        ahn[t] = h;
        attn_h_out[b * 256 + t] = h;
    }
    __syncthreads();

    {
        float a = 0.f;
        const float4* w  = (const float4*)(attn_W + (size_t)t * 256);
        const float4* xv = (const float4*)ahn;
        #pragma unroll 8
        for (int k = 0; k < 64; k++) {
            float4 wv = w[k], v = xv[k];
            a += v.x * wv.x + v.y * wv.y + v.z * wv.z + v.w * wv.w;
        }
        q_out[b * 256 + t] = a;
    }
}

// ---------------------------------------------------------------------------
// KA: fused attention, barrier-free main loop.  grid = B*16 chunks of 64 t.
// 16-lane group owns one t at a time: compute u_t (butterfly leaves sum in
// all 16 lanes), e = exp(u_t) immediately (no max: |u| <= sum|v| ~ 12, safe
// in fp32; softmax is shift-invariant), accumulate e*enc[t] into registers.
// encp and enc streams interleave; single syncthreads at the end.
// ---------------------------------------------------------------------------
__global__ __launch_bounds__(256, 4) void ka_attn(
    const float* __restrict__ enc_proj, const float* __restrict__ enc,
    const float* __restrict__ q, const float* __restrict__ v,
    float* __restrict__ u_out, float* __restrict__ ctx_part,
    float* __restrict__ s_part)
{
    const int b     = blockIdx.x >> 4;
    const int chunk = blockIdx.x & 15;
    const int tid   = threadIdx.x;
    const int lane  = tid & 63;
    const int wv    = tid >> 6;    // 0..3
    const int g     = lane >> 4;   // 16-lane group 0..3
    const int gl    = lane & 15;

    __shared__ __align__(16) float4 red[4][16][4];   // [wave][gl][c]
    __shared__ float sred[4];

    const int t0 = chunk * 64;

    float4 qv[4], vv[4];
    #pragma unroll
    for (int c = 0; c < 4; c++) {
        qv[c] = ((const float4*)(q + b * 256))[c * 16 + gl];
        vv[c] = ((const float4*)v)[c * 16 + gl];
    }

    float4 acc[4];
    #pragma unroll
    for (int c = 0; c < 4; c++) acc[c] = make_float4(0.f, 0.f, 0.f, 0.f);
    float s_acc = 0.f;

    const float* pbase = enc_proj + ((size_t)(b * T_ + t0)) * 256;
    const float* ebase = enc      + ((size_t)(b * T_ + t0)) * 256;

    #pragma unroll
    for (int pass = 0; pass < 4; pass++) {
        const int t = wv * 16 + pass * 4 + g;
        const float4* prow = (const float4*)(pbase + (size_t)t * 256);
        const float4* erow = (const float4*)(ebase + (size_t)t * 256);

        float s = 0.f;
        #pragma unroll
        for (int c = 0; c < 4; c++) {
            float4 pj = prow[c * 16 + gl];
            s += tanh_fast(pj.x + qv[c].x) * vv[c].x
               + tanh_fast(pj.y + qv[c].y) * vv[c].y
               + tanh_fast(pj.z + qv[c].z) * vv[c].z
               + tanh_fast(pj.w + qv[c].w) * vv[c].w;
        }
        // 16-lane butterfly: all 16 lanes end with the group sum
        s += __shfl_xor(s, 1, 64);
        s += __shfl_xor(s, 2, 64);
        s += __shfl_xor(s, 4, 64);
        s += __shfl_xor(s, 8, 64);
        if (gl == 0) u_out[b * T_ + t0 + t] = s;

        float e = __expf(s);
        s_acc += e;
        #pragma unroll
        for (int c = 0; c < 4; c++) {
            float4 ev = erow[c * 16 + gl];
            acc[c].x += e * ev.x; acc[c].y += e * ev.y;
            acc[c].z += e * ev.z; acc[c].w += e * ev.w;
        }
    }

    // reduce across the 4 groups of this wave (lanes differ in bits 4,5)
    #pragma unroll
    for (int c = 0; c < 4; c++) {
        acc[c].x += __shfl_xor(acc[c].x, 16, 64);
        acc[c].y += __shfl_xor(acc[c].y, 16, 64);
        acc[c].z += __shfl_xor(acc[c].z, 16, 64);
        acc[c].w += __shfl_xor(acc[c].w, 16, 64);
        acc[c].x += __shfl_xor(acc[c].x, 32, 64);
        acc[c].y += __shfl_xor(acc[c].y, 32, 64);
        acc[c].z += __shfl_xor(acc[c].z, 32, 64);
        acc[c].w += __shfl_xor(acc[c].w, 32, 64);
    }
    s_acc += __shfl_xor(s_acc, 16, 64);
    s_acc += __shfl_xor(s_acc, 32, 64);

    if (lane < 16) {
        #pragma unroll
        for (int c = 0; c < 4; c++) red[wv][gl][c] = acc[c];
    }
    if (lane == 0) sred[wv] = s_acc;
    __syncthreads();

    // cross-wave reduce + store (64 float4 = 256 d)
    if (tid < 64) {
        const int c = tid >> 4, gg = tid & 15;
        float4 a0 = red[0][gg][c], a1 = red[1][gg][c];
        float4 a2 = red[2][gg][c], a3 = red[3][gg][c];
        float4 s;
        s.x = a0.x + a1.x + a2.x + a3.x;
        s.y = a0.y + a1.y + a2.y + a3.y;
        s.z = a0.z + a1.z + a2.z + a3.z;
        s.w = a0.w + a1.w + a2.w + a3.w;
        ((float4*)ctx_part)[(size_t)(b * 16 + chunk) * 64 + c * 16 + gg] = s;
    }
    if (tid == 0)
        s_part[b * 16 + chunk] = sred[0] + sred[1] + sred[2] + sred[3];
}

// ---------------------------------------------------------------------------
// KB: combine 16 partials -> context, scores, concat1.  grid=128 (per batch)
// ---------------------------------------------------------------------------
__global__ __launch_bounds__(256) void kb_combine(
    const float* __restrict__ u, const float* __restrict__ s_part,
    const float* __restrict__ ctx_part, const float* __restrict__ attn_h,
    float* __restrict__ scores_out, float* __restrict__ ctx_out,
    float* __restrict__ concat1)
{
    const int b = blockIdx.x, tid = threadIdx.x;
    __shared__ float ssh[16];
    if (tid < 16) ssh[tid] = s_part[b * 16 + tid];
    __syncthreads();

    float S = 0.f;
    #pragma unroll
    for (int c = 0; c < 16; c++) S += ssh[c];
    float invS = 1.f / S;

    {
        float a = 0.f;
        #pragma unroll
        for (int c = 0; c < 16; c++)
            a += ctx_part[(size_t)(b * 16 + c) * 256 + tid];
        a *= invS;
        ctx_out[b * 256 + tid] = a;
        concat1[b * 512 + tid] = a;
        concat1[b * 512 + 256 + tid] = attn_h[b * 256 + tid];
    }

    #pragma unroll
    for (int i = 0; i < 4; i++) {
        int t = i * 256 + tid;
        scores_out[b * T_ + t] = __expf(u[b * T_ + t]) * invS;
    }
}

// ---------------------------------------------------------------------------
// GEMM: part[z][m][n] = A_seg[m][k0:k0+KSZ] @ W_seg[n][k0:k0+KSZ]^T
// ---------------------------------------------------------------------------
__global__ __launch_bounds__(256) void gemm512_splitk(
    const float* __restrict__ A1, const float* __restrict__ W1,
    const float* __restrict__ A2, const float* __restrict__ W2,
    float* __restrict__ part, int N, int ksPerSeg)
{
    const int n0 = blockIdx.x * 64, m0 = blockIdx.y * 64;
    const int seg = blockIdx.z / ksPerSeg, ls = blockIdx.z % ksPerSeg;
    const int KSZ = 512 / ksPerSeg;
    const float* A = seg ? A2 : A1;
    const float* W = seg ? W2 : W1;
    const int k0 = ls * KSZ;

    __shared__ __align__(16) float As[32][68];
    __shared__ __align__(16) float Ws[32][68];

    const int tid = threadIdx.x;
    const int tm = tid & 15, tn = tid >> 4;
    const int rs = tid >> 3, qs = tid & 7;

    float acc[4][4] = {};

    for (int kt = 0; kt < KSZ; kt += 32) {
        #pragma unroll
        for (int it = 0; it < 2; it++) {
            int r = rs + it * 32;
            float4 av = *(const float4*)(A + (size_t)(m0 + r) * 512 + k0 + kt + qs * 4);
            As[qs * 4 + 0][r] = av.x; As[qs * 4 + 1][r] = av.y;
            As[qs * 4 + 2][r] = av.z; As[qs * 4 + 3][r] = av.w;
            float4 wv = *(const float4*)(W + (size_t)(n0 + r) * 512 + k0 + kt + qs * 4);
            Ws[qs * 4 + 0][r] = wv.x; Ws[qs * 4 + 1][r] = wv.y;
            Ws[qs * 4 + 2][r] = wv.z; Ws[qs * 4 + 3][r] = wv.w;
        }
        __syncthreads();
        #pragma unroll
        for (int kk = 0; kk < 32; kk++) {
            float4 a = *(const float4*)&As[kk][tm * 4];
            float4 w = *(const float4*)&Ws[kk][tn * 4];
            acc[0][0] += a.x * w.x; acc[0][1] += a.x * w.y; acc[0][2] += a.x * w.z; acc[0][3] += a.x * w.w;
            acc[1][0] += a.y * w.x; acc[1][1] += a.y * w.y; acc[1][2] += a.y * w.z; acc[1][3] += a.y * w.w;
            acc[2][0] += a.z * w.x; acc[2][1] += a.z * w.y; acc[2][2] += a.z * w.z; acc[2][3] += a.z * w.w;
            acc[3][0] += a.w * w.x; acc[3][1] += a.w * w.y; acc[3][2] += a.w * w.z; acc[3][3] += a.w * w.w;
        }
        __syncthreads();
    }

    float* pb = part + ((size_t)blockIdx.z * 128 + m0) * N + n0;
    #pragma unroll
    for (int i = 0; i < 4; i++) {
        float4 o = {acc[i][0], acc[i][1], acc[i][2], acc[i][3]};
        *(float4*)(pb + (size_t)(tm * 4 + i) * N + tn * 4) = o;
    }
}

// ---------------------------------------------------------------------------
__global__ __launch_bounds__(256) void e_rnn(
    const float* __restrict__ part, const float* __restrict__ bias,
    float* __restrict__ x)
{
    const int idx = blockIdx.x * 256 + threadIdx.x;
    const int n = idx & 511;
    float a = bias[n];
    #pragma unroll
    for (int z = 0; z < 4; z++) a += part[(size_t)z * 65536 + idx];
    x[idx] = a;
}

// ---------------------------------------------------------------------------
__global__ __launch_bounds__(256) void e_lstm(
    const float* __restrict__ part,
    const float* __restrict__ bih, const float* __restrict__ bhh,
    const float* __restrict__ c_prev, const float* __restrict__ x_prev,
    float* __restrict__ h_out, float* __restrict__ c_out, float* __restrict__ x_new)
{
    const int idx = blockIdx.x * 256 + threadIdx.x;
    const int bb = idx >> 9, j = idx & 511;
    float gi = bih[j] + bhh[j];
    float gf = bih[512 + j] + bhh[512 + j];
    float gg = bih[1024 + j] + bhh[1024 + j];
    float go = bih[1536 + j] + bhh[1536 + j];
    #pragma unroll
    for (int z = 0; z < 4; z++) {
        const float* p = part + ((size_t)z * 128 + bb) * 2048;
        gi += p[j]; gf += p[512 + j]; gg += p[1024 + j]; go += p[1536 + j];
    }
    float c = sigmoidf_(gf) * c_prev[idx] + sigmoidf_(gi) * tanhf_(gg);
    float h = sigmoidf_(go) * tanhf_(c);
    h_out[idx] = h;
    c_out[idx] = c;
    x_new[idx] = x_prev[idx] + h;
}

// ---------------------------------------------------------------------------
__global__ __launch_bounds__(512) void e_lstm2_mel(
    const float* __restrict__ part,
    const float* __restrict__ bih, const float* __restrict__ bhh,
    const float* __restrict__ c_prev, const float* __restrict__ x_prev,
    const float* __restrict__ mel_W, const int* __restrict__ r_ptr,
    float* __restrict__ h_out, float* __restrict__ c_out,
    float* __restrict__ mels)
{
    const int b = blockIdx.x, j = threadIdx.x;
    __shared__ __align__(16) float xs[512];

    const int idx = b * 512 + j;
    float gi = bih[j] + bhh[j];
    float gf = bih[512 + j] + bhh[512 + j];
    float gg = bih[1024 + j] + bhh[1024 + j];
    float go = bih[1536 + j] + bhh[1536 + j];
    #pragma unroll
    for (int z = 0; z < 4; z++) {
        const float* p = part + ((size_t)z * 128 + b) * 2048;
        gi += p[j]; gf += p[512 + j]; gg += p[1024 + j]; go += p[1536 + j];
    }
    float c = sigmoidf_(gf) * c_prev[idx] + sigmoidf_(gi) * tanhf_(gg);
    float h = sigmoidf_(go) * tanhf_(c);
    h_out[idx] = h;
    c_out[idx] = c;
    xs[j] = x_prev[idx] + h;
    __syncthreads();

    const int r = r_ptr[0];
    const int tot = 80 * r;
    for (int n = j; n < tot; n += 512) {
        int m = n / r, rr = n % r;
        const float4* w  = (const float4*)(mel_W + (size_t)(m * 20 + rr) * 512);
        const float4* xv = (const float4*)xs;
        float a = 0.f;
        #pragma unroll 8
        for (int k = 0; k < 128; k++) {
            float4 wv = w[k], vv = xv[k];
            a += wv.x * vv.x + wv.y * vv.y + wv.z * vv.z + wv.w * vv.w;
        }
        mels[(size_t)b * tot + n] = a;
    }
}

// ---------------------------------------------------------------------------
extern "C" void kernel_launch(void* const* d_in, const int* in_sizes, int n_in,
                              void* d_out, int out_size, void* d_ws, size_t ws_size,
                              hipStream_t stream)
{
    const float* enc   = (const float*)d_in[0];
    const float* encp  = (const float*)d_in[1];
    const float* pre   = (const float*)d_in[2];
    const float* ah_in = (const float*)d_in[3];
    const float* r1h   = (const float*)d_in[4];
    const float* r2h   = (const float*)d_in[5];
    const float* r1c   = (const float*)d_in[6];
    const float* r2c   = (const float*)d_in[7];
    const float* cvec  = (const float*)d_in[8];
    const float* fc1W  = (const float*)d_in[9];
    const float* fc1b  = (const float*)d_in[10];
    const float* fc2W  = (const float*)d_in[11];
    const float* fc2b  = (const float*)d_in[12];
    const float* attnW = (const float*)d_in[13];
    const float* attnv = (const float*)d_in[14];
    const float* gWih  = (const float*)d_in[15];
    const float* gWhh  = (const float*)d_in[16];
    const float* gbih  = (const float*)d_in[17];
    const float* gbhh  = (const float*)d_in[18];
    const float* rinW  = (const float*)d_in[19];
    const float* rinb  = (const float*)d_in[20];
    const float* l1Wih = (const float*)d_in[21];
    const float* l1Whh = (const float*)d_in[22];
    const float* l1bih = (const float*)d_in[23];
    const float* l1bhh = (const float*)d_in[24];
    const float* l2Wih = (const float*)d_in[25];
    const float* l2Whh = (const float*)d_in[26];
    const float* l2bih = (const float*)d_in[27];
    const float* l2bhh = (const float*)d_in[28];
    const float* melW  = (const float*)d_in[29];
    const int*   rp    = (const int*)d_in[30];

    float* out = (float*)d_out;
    float* o_mels  = out + 0;        // 128*80*2
    float* o_scor  = out + 20480;    // 128*1024
    float* o_attnh = out + 151552;   // 128*256
    float* o_r1h   = out + 184320;   // 128*512
    float* o_r2h   = out + 249856;
    float* o_r1c   = out + 315392;
    float* o_r2c   = out + 380928;
    float* o_ctx   = out + 446464;   // 128*256

    float* ws     = (float*)d_ws;
    float* w_q    = ws + 0;          // 32768
    float* w_u    = ws + 32768;      // 131072
    float* w_s    = ws + 163840;     // 2048
    float* w_ctxp = ws + 165888;     // 16*128*256 = 524288
    float* w_cat1 = ws + 692224;     // 65536
    float* w_x    = ws + 757760;     // 65536
    float* w_x2   = ws + 823296;     // 65536
    float* w_part = ws + 888832;     // 4*128*2048 = 1048576

    // front-end scratch reuses the w_part region (free until the GEMM phase)
    float* w_p2 = w_part;            // 128*128
    float* w_gi = w_part + 16384;    // 128*768
    float* w_gh = w_part + 114688;   // 128*768

    hipLaunchKernelGGL(k1a_prenet, dim3(128), dim3(256), 0, stream,
                       pre, fc1W, fc1b, fc2W, fc2b, w_p2);

    hipLaunchKernelGGL(k1b_gru_gemv, dim3(3, 64), dim3(256), 0, stream,
                       cvec, w_p2, ah_in, gWih, gWhh, gbih, gbhh, w_gi, w_gh);

    hipLaunchKernelGGL(k1c_gates_q, dim3(128), dim3(256), 0, stream,
                       w_gi, w_gh, ah_in, attnW, o_attnh, w_q);

    hipLaunchKernelGGL(ka_attn, dim3(2048), dim3(256), 0, stream,
                       encp, enc, w_q, attnv, w_u, w_ctxp, w_s);

    hipLaunchKernelGGL(kb_combine, dim3(128), dim3(256), 0, stream,
                       w_u, w_s, w_ctxp, o_attnh, o_scor, o_ctx, w_cat1);

    // rnn_in: K=512, 4 k-slices
    hipLaunchKernelGGL(gemm512_splitk, dim3(8, 2, 4), dim3(256), 0, stream,
                       w_cat1, rinW, w_cat1, rinW, w_part, 512, 4);
    hipLaunchKernelGGL(e_rnn, dim3(256), dim3(256), 0, stream, w_part, rinb, w_x);

    // LSTM 1
    hipLaunchKernelGGL(gemm512_splitk, dim3(32, 2, 4), dim3(256), 0, stream,
                       w_x, l1Wih, r1h, l1Whh, w_part, 2048, 2);
    hipLaunchKernelGGL(e_lstm, dim3(256), dim3(256), 0, stream,
                       w_part, l1bih, l1bhh, r1c, w_x, o_r1h, o_r1c, w_x2);

    // LSTM 2 + mel
    hipLaunchKernelGGL(gemm512_splitk, dim3(32, 2, 4), dim3(256), 0, stream,
                       w_x2, l2Wih, r2h, l2Whh, w_part, 2048, 2);
    hipLaunchKernelGGL(e_lstm2_mel, dim3(128), dim3(512), 0, stream,
                       w_part, l2bih, l2bhh, r2c, w_x2, melW, rp,
                       o_r2h, o_r2c, o_mels);
}

// Round 6
// 138.335 us; speedup vs baseline: 1.3708x; 1.1189x over previous
//
#include <hip/hip_runtime.h>
#include <math.h>

#define B_   128
#define T_   1024
#define D_   256
#define L_   512

__device__ __forceinline__ float sigmoidf_(float x) {
    return 1.f / (1.f + __expf(-x));
}
__device__ __forceinline__ float tanhf_(float x) {
    x = fminf(fmaxf(x, -15.f), 15.f);
    float e = __expf(2.f * x);
    return (e - 1.f) / (e + 1.f);
}
// tanh(x) = 1 - 2/(exp(2x)+1); exact identity, v_exp + v_rcp
__device__ __forceinline__ float tanh_fast(float x) {
    float e = __expf(2.f * x);
    return 1.f - 2.f * __builtin_amdgcn_rcpf(e + 1.f);
}
__device__ __forceinline__ float waveReduceSum(float v) {
    #pragma unroll
    for (int o = 32; o > 0; o >>= 1) v += __shfl_xor(v, o, 64);
    return v;
}

// ---------------------------------------------------------------------------
// K1a: prenet per batch.  grid=128, block=256
// ---------------------------------------------------------------------------
__global__ __launch_bounds__(256) void k1a_prenet(
    const float* __restrict__ prenet_in,
    const float* __restrict__ fc1_W, const float* __restrict__ fc1_b,
    const float* __restrict__ fc2_W, const float* __restrict__ fc2_b,
    float* __restrict__ p2_out)
{
    const int b = blockIdx.x, t = threadIdx.x;
    __shared__ __align__(16) float pin[80];
    __shared__ __align__(16) float p1[256];

    if (t < 80) pin[t] = prenet_in[b * 80 + t];
    __syncthreads();

    {
        float a = fc1_b[t];
        const float4* w  = (const float4*)(fc1_W + t * 80);
        const float4* xv = (const float4*)pin;
        #pragma unroll
        for (int k = 0; k < 20; k++) {
            float4 wv = w[k], v = xv[k];
            a += v.x * wv.x + v.y * wv.y + v.z * wv.z + v.w * wv.w;
        }
        p1[t] = fmaxf(a, 0.f);
    }
    __syncthreads();

    if (t < 128) {
        float a = fc2_b[t];
        const float4* w  = (const float4*)(fc2_W + t * 256);
        const float4* xv = (const float4*)p1;
        #pragma unroll 8
        for (int k = 0; k < 64; k++) {
            float4 wv = w[k], v = xv[k];
            a += v.x * wv.x + v.y * wv.y + v.z * wv.z + v.w * wv.w;
        }
        p2_out[b * 128 + t] = fmaxf(a, 0.f);
    }
}

// ---------------------------------------------------------------------------
// K1b: GRU gate GEMVs.  grid = (3 j-tiles, 64 batch-pairs), block = 256.
// ---------------------------------------------------------------------------
__global__ __launch_bounds__(256) void k1b_gru_gemv(
    const float* __restrict__ context_vec, const float* __restrict__ p2,
    const float* __restrict__ attn_hidden,
    const float* __restrict__ gru_Wih, const float* __restrict__ gru_Whh,
    const float* __restrict__ gru_bih, const float* __restrict__ gru_bhh,
    float* __restrict__ gi_out, float* __restrict__ gh_out)
{
    const int t = threadIdx.x;
    const int j = blockIdx.x * 256 + t;
    const int b0 = blockIdx.y * 2;

    __shared__ __align__(16) float xs[2][384];
    __shared__ __align__(16) float hs[2][256];

    for (int i = t; i < 768; i += 256) {
        int bb = i / 384, k = i % 384;
        xs[bb][k] = (k < 256) ? context_vec[(b0 + bb) * 256 + k]
                              : p2[(b0 + bb) * 128 + (k - 256)];
    }
    for (int i = t; i < 512; i += 256) {
        hs[i / 256][i % 256] = attn_hidden[(b0 + i / 256) * 256 + (i % 256)];
    }
    __syncthreads();

    {
        float a0 = gru_bih[j], a1 = a0;
        const float4* w  = (const float4*)(gru_Wih + (size_t)j * 384);
        const float4* x0 = (const float4*)xs[0];
        const float4* x1 = (const float4*)xs[1];
        #pragma unroll 8
        for (int k = 0; k < 96; k++) {
            float4 wv = w[k], v0 = x0[k], v1 = x1[k];
            a0 += v0.x * wv.x + v0.y * wv.y + v0.z * wv.z + v0.w * wv.w;
            a1 += v1.x * wv.x + v1.y * wv.y + v1.z * wv.z + v1.w * wv.w;
        }
        gi_out[(size_t)(b0 + 0) * 768 + j] = a0;
        gi_out[(size_t)(b0 + 1) * 768 + j] = a1;
    }
    {
        float a0 = gru_bhh[j], a1 = a0;
        const float4* w  = (const float4*)(gru_Whh + (size_t)j * 256);
        const float4* x0 = (const float4*)hs[0];
        const float4* x1 = (const float4*)hs[1];
        #pragma unroll 8
        for (int k = 0; k < 64; k++) {
            float4 wv = w[k], v0 = x0[k], v1 = x1[k];
            a0 += v0.x * wv.x + v0.y * wv.y + v0.z * wv.z + v0.w * wv.w;
            a1 += v1.x * wv.x + v1.y * wv.y + v1.z * wv.z + v1.w * wv.w;
        }
        gh_out[(size_t)(b0 + 0) * 768 + j] = a0;
        gh_out[(size_t)(b0 + 1) * 768 + j] = a1;
    }
}

// ---------------------------------------------------------------------------
// K1c: GRU gates + q = attn_h @ attn_W.T.   grid=128, block=256
// ---------------------------------------------------------------------------
__global__ __launch_bounds__(256) void k1c_gates_q(
    const float* __restrict__ gi, const float* __restrict__ gh,
    const float* __restrict__ attn_hidden, const float* __restrict__ attn_W,
    float* __restrict__ attn_h_out, float* __restrict__ q_out)
{
    const int b = blockIdx.x, t = threadIdx.x;
    __shared__ __align__(16) float ahn[256];

    {
        float hp = attn_hidden[b * 256 + t];
        float rg = sigmoidf_(gi[(size_t)b * 768 + t]       + gh[(size_t)b * 768 + t]);
        float zg = sigmoidf_(gi[(size_t)b * 768 + 256 + t] + gh[(size_t)b * 768 + 256 + t]);
        float ng = tanhf_(gi[(size_t)b * 768 + 512 + t] + rg * gh[(size_t)b * 768 + 512 + t]);
        float h  = (1.f - zg) * ng + zg * hp;
        ahn[t] = h;
        attn_h_out[b * 256 + t] = h;
    }
    __syncthreads();

    {
        float a = 0.f;
        const float4* w  = (const float4*)(attn_W + (size_t)t * 256);
        const float4* xv = (const float4*)ahn;
        #pragma unroll 8
        for (int k = 0; k < 64; k++) {
            float4 wv = w[k], v = xv[k];
            a += v.x * wv.x + v.y * wv.y + v.z * wv.z + v.w * wv.w;
        }
        q_out[b * 256 + t] = a;
    }
}

// ---------------------------------------------------------------------------
// KA: fused attention, 1 wave per 64-row chunk.  grid = B*16, block = 64.
// stage1: LANE OWNS A ROW -> u computed fully in-lane, zero shuffles,
//         16 independent float4 loads per lane (q,v broadcast from LDS).
// stage2: e=exp(u) (no max; |u|<=sum|v|~10, fp32-safe, softmax shift-inv).
//         one 6-shfl reduce for s.
// stage3: stream 64 contiguous enc rows (1KB/instr), e broadcast from LDS,
//         per-lane float4 accumulator, zero shuffles, direct coalesced store.
// ---------------------------------------------------------------------------
__global__ __launch_bounds__(64, 2) void ka_attn(
    const float* __restrict__ enc_proj, const float* __restrict__ enc,
    const float* __restrict__ q, const float* __restrict__ v,
    float* __restrict__ u_out, float* __restrict__ ctx_part,
    float* __restrict__ s_part)
{
    const int b     = blockIdx.x >> 4;
    const int chunk = blockIdx.x & 15;
    const int lane  = threadIdx.x;      // 0..63
    const int t0    = chunk * 64;

    __shared__ __align__(16) float qs[256];
    __shared__ __align__(16) float vs[256];
    __shared__ __align__(16) float el[64];

    // stage q, v into LDS (64 lanes x float4 = 256 floats each)
    ((float4*)qs)[lane] = ((const float4*)(q + b * 256))[lane];
    ((float4*)vs)[lane] = ((const float4*)v)[lane];
    __syncthreads();

    // ---- stage 1: lane owns row (t0 + lane) ----
    const float4* prow = (const float4*)(enc_proj + ((size_t)(b * T_ + t0 + lane)) * 256);
    const float4* qv4  = (const float4*)qs;
    const float4* vv4  = (const float4*)vs;

    float s0 = 0.f, s1 = 0.f, s2 = 0.f, s3 = 0.f;
    #pragma unroll
    for (int k = 0; k < 16; k += 4) {
        float4 p0 = prow[k + 0], p1 = prow[k + 1], p2 = prow[k + 2], p3 = prow[k + 3];
        float4 q0 = qv4[k + 0],  q1 = qv4[k + 1],  q2 = qv4[k + 2],  q3 = qv4[k + 3];
        float4 v0 = vv4[k + 0],  v1 = vv4[k + 1],  v2 = vv4[k + 2],  v3 = vv4[k + 3];
        s0 += tanh_fast(p0.x + q0.x) * v0.x + tanh_fast(p0.y + q0.y) * v0.y
            + tanh_fast(p0.z + q0.z) * v0.z + tanh_fast(p0.w + q0.w) * v0.w;
        s1 += tanh_fast(p1.x + q1.x) * v1.x + tanh_fast(p1.y + q1.y) * v1.y
            + tanh_fast(p1.z + q1.z) * v1.z + tanh_fast(p1.w + q1.w) * v1.w;
        s2 += tanh_fast(p2.x + q2.x) * v2.x + tanh_fast(p2.y + q2.y) * v2.y
            + tanh_fast(p2.z + q2.z) * v2.z + tanh_fast(p2.w + q2.w) * v2.w;
        s3 += tanh_fast(p3.x + q3.x) * v3.x + tanh_fast(p3.y + q3.y) * v3.y
            + tanh_fast(p3.z + q3.z) * v3.z + tanh_fast(p3.w + q3.w) * v3.w;
    }
    float u = (s0 + s1) + (s2 + s3);
    u_out[b * T_ + t0 + lane] = u;                 // coalesced 256B store

    float e = __expf(u);
    el[lane] = e;
    float ssum = waveReduceSum(e);
    if (lane == 0) s_part[b * 16 + chunk] = ssum;
    __syncthreads();

    // ---- stage 3: stream 64 contiguous enc rows ----
    const float4* erow = (const float4*)(enc + ((size_t)(b * T_ + t0)) * 256);
    const float4* e4p  = (const float4*)el;
    float4 accA = {0.f, 0.f, 0.f, 0.f}, accB = {0.f, 0.f, 0.f, 0.f};

    #pragma unroll 4
    for (int t = 0; t < 64; t += 4) {
        float4 e4 = e4p[t >> 2];
        float4 r0 = erow[(size_t)(t + 0) * 64 + lane];
        float4 r1 = erow[(size_t)(t + 1) * 64 + lane];
        float4 r2 = erow[(size_t)(t + 2) * 64 + lane];
        float4 r3 = erow[(size_t)(t + 3) * 64 + lane];
        accA.x += e4.x * r0.x; accA.y += e4.x * r0.y; accA.z += e4.x * r0.z; accA.w += e4.x * r0.w;
        accB.x += e4.y * r1.x; accB.y += e4.y * r1.y; accB.z += e4.y * r1.z; accB.w += e4.y * r1.w;
        accA.x += e4.z * r2.x; accA.y += e4.z * r2.y; accA.z += e4.z * r2.z; accA.w += e4.z * r2.w;
        accB.x += e4.w * r3.x; accB.y += e4.w * r3.y; accB.z += e4.w * r3.z; accB.w += e4.w * r3.w;
    }
    accA.x += accB.x; accA.y += accB.y; accA.z += accB.z; accA.w += accB.w;
    ((float4*)ctx_part)[(size_t)(b * 16 + chunk) * 64 + lane] = accA;   // coalesced 1KB
}

// ---------------------------------------------------------------------------
// KB: combine 16 partials -> context, scores, concat1.  grid=128 (per batch)
// ---------------------------------------------------------------------------
__global__ __launch_bounds__(256) void kb_combine(
    const float* __restrict__ u, const float* __restrict__ s_part,
    const float* __restrict__ ctx_part, const float* __restrict__ attn_h,
    float* __restrict__ scores_out, float* __restrict__ ctx_out,
    float* __restrict__ concat1)
{
    const int b = blockIdx.x, tid = threadIdx.x;
    __shared__ float ssh[16];
    if (tid < 16) ssh[tid] = s_part[b * 16 + tid];
    __syncthreads();

    float S = 0.f;
    #pragma unroll
    for (int c = 0; c < 16; c++) S += ssh[c];
    float invS = 1.f / S;

    {
        float a = 0.f;
        #pragma unroll
        for (int c = 0; c < 16; c++)
            a += ctx_part[(size_t)(b * 16 + c) * 256 + tid];
        a *= invS;
        ctx_out[b * 256 + tid] = a;
        concat1[b * 512 + tid] = a;
        concat1[b * 512 + 256 + tid] = attn_h[b * 256 + tid];
    }

    #pragma unroll
    for (int i = 0; i < 4; i++) {
        int t = i * 256 + tid;
        scores_out[b * T_ + t] = __expf(u[b * T_ + t]) * invS;
    }
}

// ---------------------------------------------------------------------------
// GEMM: part[z][m][n] = A_seg[m][k0:k0+KSZ] @ W_seg[n][k0:k0+KSZ]^T
// ---------------------------------------------------------------------------
__global__ __launch_bounds__(256) void gemm512_splitk(
    const float* __restrict__ A1, const float* __restrict__ W1,
    const float* __restrict__ A2, const float* __restrict__ W2,
    float* __restrict__ part, int N, int ksPerSeg)
{
    const int n0 = blockIdx.x * 64, m0 = blockIdx.y * 64;
    const int seg = blockIdx.z / ksPerSeg, ls = blockIdx.z % ksPerSeg;
    const int KSZ = 512 / ksPerSeg;
    const float* A = seg ? A2 : A1;
    const float* W = seg ? W2 : W1;
    const int k0 = ls * KSZ;

    __shared__ __align__(16) float As[32][68];
    __shared__ __align__(16) float Ws[32][68];

    const int tid = threadIdx.x;
    const int tm = tid & 15, tn = tid >> 4;
    const int rs = tid >> 3, qs = tid & 7;

    float acc[4][4] = {};

    for (int kt = 0; kt < KSZ; kt += 32) {
        #pragma unroll
        for (int it = 0; it < 2; it++) {
            int r = rs + it * 32;
            float4 av = *(const float4*)(A + (size_t)(m0 + r) * 512 + k0 + kt + qs * 4);
            As[qs * 4 + 0][r] = av.x; As[qs * 4 + 1][r] = av.y;
            As[qs * 4 + 2][r] = av.z; As[qs * 4 + 3][r] = av.w;
            float4 wv = *(const float4*)(W + (size_t)(n0 + r) * 512 + k0 + kt + qs * 4);
            Ws[qs * 4 + 0][r] = wv.x; Ws[qs * 4 + 1][r] = wv.y;
            Ws[qs * 4 + 2][r] = wv.z; Ws[qs * 4 + 3][r] = wv.w;
        }
        __syncthreads();
        #pragma unroll
        for (int kk = 0; kk < 32; kk++) {
            float4 a = *(const float4*)&As[kk][tm * 4];
            float4 w = *(const float4*)&Ws[kk][tn * 4];
            acc[0][0] += a.x * w.x; acc[0][1] += a.x * w.y; acc[0][2] += a.x * w.z; acc[0][3] += a.x * w.w;
            acc[1][0] += a.y * w.x; acc[1][1] += a.y * w.y; acc[1][2] += a.y * w.z; acc[1][3] += a.y * w.w;
            acc[2][0] += a.z * w.x; acc[2][1] += a.z * w.y; acc[2][2] += a.z * w.z; acc[2][3] += a.z * w.w;
            acc[3][0] += a.w * w.x; acc[3][1] += a.w * w.y; acc[3][2] += a.w * w.z; acc[3][3] += a.w * w.w;
        }
        __syncthreads();
    }

    float* pb = part + ((size_t)blockIdx.z * 128 + m0) * N + n0;
    #pragma unroll
    for (int i = 0; i < 4; i++) {
        float4 o = {acc[i][0], acc[i][1], acc[i][2], acc[i][3]};
        *(float4*)(pb + (size_t)(tm * 4 + i) * N + tn * 4) = o;
    }
}

// ---------------------------------------------------------------------------
__global__ __launch_bounds__(256) void e_rnn(
    const float* __restrict__ part, const float* __restrict__ bias,
    float* __restrict__ x)
{
    const int idx = blockIdx.x * 256 + threadIdx.x;
    const int n = idx & 511;
    float a = bias[n];
    #pragma unroll
    for (int z = 0; z < 4; z++) a += part[(size_t)z * 65536 + idx];
    x[idx] = a;
}

// ---------------------------------------------------------------------------
__global__ __launch_bounds__(256) void e_lstm(
    const float* __restrict__ part,
    const float* __restrict__ bih, const float* __restrict__ bhh,
    const float* __restrict__ c_prev, const float* __restrict__ x_prev,
    float* __restrict__ h_out, float* __restrict__ c_out, float* __restrict__ x_new)
{
    const int idx = blockIdx.x * 256 + threadIdx.x;
    const int bb = idx >> 9, j = idx & 511;
    float gi = bih[j] + bhh[j];
    float gf = bih[512 + j] + bhh[512 + j];
    float gg = bih[1024 + j] + bhh[1024 + j];
    float go = bih[1536 + j] + bhh[1536 + j];
    #pragma unroll
    for (int z = 0; z < 4; z++) {
        const float* p = part + ((size_t)z * 128 + bb) * 2048;
        gi += p[j]; gf += p[512 + j]; gg += p[1024 + j]; go += p[1536 + j];
    }
    float c = sigmoidf_(gf) * c_prev[idx] + sigmoidf_(gi) * tanhf_(gg);
    float h = sigmoidf_(go) * tanhf_(c);
    h_out[idx] = h;
    c_out[idx] = c;
    x_new[idx] = x_prev[idx] + h;
}

// ---------------------------------------------------------------------------
__global__ __launch_bounds__(512) void e_lstm2_mel(
    const float* __restrict__ part,
    const float* __restrict__ bih, const float* __restrict__ bhh,
    const float* __restrict__ c_prev, const float* __restrict__ x_prev,
    const float* __restrict__ mel_W, const int* __restrict__ r_ptr,
    float* __restrict__ h_out, float* __restrict__ c_out,
    float* __restrict__ mels)
{
    const int b = blockIdx.x, j = threadIdx.x;
    __shared__ __align__(16) float xs[512];

    const int idx = b * 512 + j;
    float gi = bih[j] + bhh[j];
    float gf = bih[512 + j] + bhh[512 + j];
    float gg = bih[1024 + j] + bhh[1024 + j];
    float go = bih[1536 + j] + bhh[1536 + j];
    #pragma unroll
    for (int z = 0; z < 4; z++) {
        const float* p = part + ((size_t)z * 128 + b) * 2048;
        gi += p[j]; gf += p[512 + j]; gg += p[1024 + j]; go += p[1536 + j];
    }
    float c = sigmoidf_(gf) * c_prev[idx] + sigmoidf_(gi) * tanhf_(gg);
    float h = sigmoidf_(go) * tanhf_(c);
    h_out[idx] = h;
    c_out[idx] = c;
    xs[j] = x_prev[idx] + h;
    __syncthreads();

    const int r = r_ptr[0];
    const int tot = 80 * r;
    for (int n = j; n < tot; n += 512) {
        int m = n / r, rr = n % r;
        const float4* w  = (const float4*)(mel_W + (size_t)(m * 20 + rr) * 512);
        const float4* xv = (const float4*)xs;
        float a = 0.f;
        #pragma unroll 8
        for (int k = 0; k < 128; k++) {
            float4 wv = w[k], vv = xv[k];
            a += wv.x * vv.x + wv.y * vv.y + wv.z * vv.z + wv.w * vv.w;
        }
        mels[(size_t)b * tot + n] = a;
    }
}

// ---------------------------------------------------------------------------
extern "C" void kernel_launch(void* const* d_in, const int* in_sizes, int n_in,
                              void* d_out, int out_size, void* d_ws, size_t ws_size,
                              hipStream_t stream)
{
    const float* enc   = (const float*)d_in[0];
    const float* encp  = (const float*)d_in[1];
    const float* pre   = (const float*)d_in[2];
    const float* ah_in = (const float*)d_in[3];
    const float* r1h   = (const float*)d_in[4];
    const float* r2h   = (const float*)d_in[5];
    const float* r1c   = (const float*)d_in[6];
    const float* r2c   = (const float*)d_in[7];
    const float* cvec  = (const float*)d_in[8];
    const float* fc1W  = (const float*)d_in[9];
    const float* fc1b  = (const float*)d_in[10];
    const float* fc2W  = (const float*)d_in[11];
    const float* fc2b  = (const float*)d_in[12];
    const float* attnW = (const float*)d_in[13];
    const float* attnv = (const float*)d_in[14];
    const float* gWih  = (const float*)d_in[15];
    const float* gWhh  = (const float*)d_in[16];
    const float* gbih  = (const float*)d_in[17];
    const float* gbhh  = (const float*)d_in[18];
    const float* rinW  = (const float*)d_in[19];
    const float* rinb  = (const float*)d_in[20];
    const float* l1Wih = (const float*)d_in[21];
    const float* l1Whh = (const float*)d_in[22];
    const float* l1bih = (const float*)d_in[23];
    const float* l1bhh = (const float*)d_in[24];
    const float* l2Wih = (const float*)d_in[25];
    const float* l2Whh = (const float*)d_in[26];
    const float* l2bih = (const float*)d_in[27];
    const float* l2bhh = (const float*)d_in[28];
    const float* melW  = (const float*)d_in[29];
    const int*   rp    = (const int*)d_in[30];

    float* out = (float*)d_out;
    float* o_mels  = out + 0;        // 128*80*2
    float* o_scor  = out + 20480;    // 128*1024
    float* o_attnh = out + 151552;   // 128*256
    float* o_r1h   = out + 184320;   // 128*512
    float* o_r2h   = out + 249856;
    float* o_r1c   = out + 315392;
    float* o_r2c   = out + 380928;
    float* o_ctx   = out + 446464;   // 128*256

    float* ws     = (float*)d_ws;
    float* w_q    = ws + 0;          // 32768
    float* w_u    = ws + 32768;      // 131072
    float* w_s    = ws + 163840;     // 2048
    float* w_ctxp = ws + 165888;     // 16*128*256 = 524288
    float* w_cat1 = ws + 692224;     // 65536
    float* w_x    = ws + 757760;     // 65536
    float* w_x2   = ws + 823296;     // 65536
    float* w_part = ws + 888832;     // 4*128*2048 = 1048576

    // front-end scratch reuses the w_part region (free until the GEMM phase)
    float* w_p2 = w_part;            // 128*128
    float* w_gi = w_part + 16384;    // 128*768
    float* w_gh = w_part + 114688;   // 128*768

    hipLaunchKernelGGL(k1a_prenet, dim3(128), dim3(256), 0, stream,
                       pre, fc1W, fc1b, fc2W, fc2b, w_p2);

    hipLaunchKernelGGL(k1b_gru_gemv, dim3(3, 64), dim3(256), 0, stream,
                       cvec, w_p2, ah_in, gWih, gWhh, gbih, gbhh, w_gi, w_gh);

    hipLaunchKernelGGL(k1c_gates_q, dim3(128), dim3(256), 0, stream,
                       w_gi, w_gh, ah_in, attnW, o_attnh, w_q);

    hipLaunchKernelGGL(ka_attn, dim3(2048), dim3(64), 0, stream,
                       encp, enc, w_q, attnv, w_u, w_ctxp, w_s);

    hipLaunchKernelGGL(kb_combine, dim3(128), dim3(256), 0, stream,
                       w_u, w_s, w_ctxp, o_attnh, o_scor, o_ctx, w_cat1);

    // rnn_in: K=512, 4 k-slices
    hipLaunchKernelGGL(gemm512_splitk, dim3(8, 2, 4), dim3(256), 0, stream,
                       w_cat1, rinW, w_cat1, rinW, w_part, 512, 4);
    hipLaunchKernelGGL(e_rnn, dim3(256), dim3(256), 0, stream, w_part, rinb, w_x);

    // LSTM 1
    hipLaunchKernelGGL(gemm512_splitk, dim3(32, 2, 4), dim3(256), 0, stream,
                       w_x, l1Wih, r1h, l1Whh, w_part, 2048, 2);
    hipLaunchKernelGGL(e_lstm, dim3(256), dim3(256), 0, stream,
                       w_part, l1bih, l1bhh, r1c, w_x, o_r1h, o_r1c, w_x2);

    // LSTM 2 + mel
    hipLaunchKernelGGL(gemm512_splitk, dim3(32, 2, 4), dim3(256), 0, stream,
                       w_x2, l2Wih, r2h, l2Whh, w_part, 2048, 2);
    hipLaunchKernelGGL(e_lstm2_mel, dim3(128), dim3(512), 0, stream,
                       w_part, l2bih, l2bhh, r2c, w_x2, melW, rp,
                       o_r2h, o_r2c, o_mels);
}